// Round 1
// baseline (89.563 us; speedup 1.0000x reference)
//
#include <hip/hip_runtime.h>
#include <math.h>

// Problem shape (from reference setup_inputs): S=4096, B=32, H=1024, fp32.
// energies[b,s] = dot(hidden[0,b,:], enc[s,b,:]) ; out = softmax over s, [B,1,S].

#define S_DIM 4096
#define B_DIM 32
#define H_DIM 1024

__device__ __forceinline__ float wave_reduce_sum(float v) {
#pragma unroll
    for (int off = 32; off > 0; off >>= 1)
        v += __shfl_xor(v, off, 64);
    return v;
}

__device__ __forceinline__ float wave_reduce_max(float v) {
#pragma unroll
    for (int off = 32; off > 0; off >>= 1)
        v = fmaxf(v, __shfl_xor(v, off, 64));
    return v;
}

// Stage 1: one wave per (s, b) dot product over H=1024 contiguous floats.
// 256 threads/block = 4 waves = 4 dot products per block.
__global__ __launch_bounds__(256) void energies_kernel(
        const float* __restrict__ hidden,    // [B, H]   (hidden[0])
        const float* __restrict__ enc,       // [S, B, H]
        float* __restrict__ energies)        // [B, S]  (== d_out)
{
    const int wave_g = (blockIdx.x * blockDim.x + threadIdx.x) >> 6;
    const int lane   = threadIdx.x & 63;
    if (wave_g >= S_DIM * B_DIM) return;
    const int s = wave_g / B_DIM;
    const int b = wave_g % B_DIM;

    const float4* e4 = reinterpret_cast<const float4*>(
        enc + ((size_t)s * B_DIM + b) * H_DIM);
    const float4* h4 = reinterpret_cast<const float4*>(
        hidden + (size_t)b * H_DIM);

    float acc = 0.0f;
#pragma unroll
    for (int it = 0; it < H_DIM / (64 * 4); ++it) {   // 4 iters
        const float4 ev = e4[lane + it * 64];
        const float4 hv = h4[lane + it * 64];
        acc = fmaf(ev.x, hv.x, acc);
        acc = fmaf(ev.y, hv.y, acc);
        acc = fmaf(ev.z, hv.z, acc);
        acc = fmaf(ev.w, hv.w, acc);
    }
    acc = wave_reduce_sum(acc);
    if (lane == 0) energies[(size_t)b * S_DIM + s] = acc;
}

// Stage 2: in-place row softmax. One block (256 threads) per b.
// Each thread owns 4 float4 = 16 elements of the 4096-long row.
__global__ __launch_bounds__(256) void softmax_kernel(float* __restrict__ out)
{
    const int b   = blockIdx.x;
    const int tid = threadIdx.x;
    const int wid = tid >> 6;
    const int lane = tid & 63;
    float* row = out + (size_t)b * S_DIM;
    float4* row4 = reinterpret_cast<float4*>(row);

    __shared__ float red[4];

    float4 v[4];
    float m = -INFINITY;
#pragma unroll
    for (int i = 0; i < 4; ++i) {
        v[i] = row4[tid + i * 256];
        m = fmaxf(m, fmaxf(fmaxf(v[i].x, v[i].y), fmaxf(v[i].z, v[i].w)));
    }
    m = wave_reduce_max(m);
    if (lane == 0) red[wid] = m;
    __syncthreads();
    m = fmaxf(fmaxf(red[0], red[1]), fmaxf(red[2], red[3]));

    float sum = 0.0f;
#pragma unroll
    for (int i = 0; i < 4; ++i) {
        v[i].x = __expf(v[i].x - m);
        v[i].y = __expf(v[i].y - m);
        v[i].z = __expf(v[i].z - m);
        v[i].w = __expf(v[i].w - m);
        sum += v[i].x + v[i].y + v[i].z + v[i].w;
    }
    sum = wave_reduce_sum(sum);
    __syncthreads();                 // reuse red[]
    if (lane == 0) red[wid] = sum;
    __syncthreads();
    sum = red[0] + red[1] + red[2] + red[3];
    const float inv = 1.0f / sum;

#pragma unroll
    for (int i = 0; i < 4; ++i) {
        v[i].x *= inv; v[i].y *= inv; v[i].z *= inv; v[i].w *= inv;
        row4[tid + i * 256] = v[i];
    }
}

extern "C" void kernel_launch(void* const* d_in, const int* in_sizes, int n_in,
                              void* d_out, int out_size, void* d_ws, size_t ws_size,
                              hipStream_t stream) {
    const float* hidden = (const float*)d_in[0];   // [1, B, H]
    const float* enc    = (const float*)d_in[1];   // [S, B, H]
    float* out          = (float*)d_out;           // [B, 1, S] -> B*S floats

    // Stage 1: S*B waves, 4 waves per 256-thread block.
    const int total_waves = S_DIM * B_DIM;               // 131072
    const int blocks1 = total_waves / 4;                 // 32768
    energies_kernel<<<blocks1, 256, 0, stream>>>(hidden, enc, out);

    // Stage 2: one block per batch row.
    softmax_kernel<<<B_DIM, 256, 0, stream>>>(out);
}